// Round 2
// baseline (340.155 us; speedup 1.0000x reference)
//
#include <hip/hip_runtime.h>
#include <math.h>

// ---------------------------------------------------------------------------
// 2-layer GCN: out = A_hat( tanh( A_hat(X W1) + b1 ) ) W2 + b2
// A_hat = D^-1/2 (A + I) D^-1/2, built as dst-CSR each call (ws is re-poisoned).
// Self-loops handled analytically (acc init = h[node]*dis^2), CSR holds only
// the E real edges. Transform-then-aggregate in both layers (layer 2
// aggregates at width 64, halving gather traffic).
// ---------------------------------------------------------------------------

// --- edge dtype probe: int64 layout => odd 32-bit words all zero -----------
__global__ void detect_kernel(const int* __restrict__ ei32, int* __restrict__ flag) {
    if (blockIdx.x == 0 && threadIdx.x == 0) {
        int is64 = 1;
        for (int k = 1; k < 64; k += 2)
            if (ei32[k] != 0) { is64 = 0; break; }
        *flag = is64;
    }
}

// emit clean int32 edge array regardless of input layout
__global__ __launch_bounds__(256) void normalize_kernel(const int* __restrict__ ei32,
                                                        const int* __restrict__ flag,
                                                        int* __restrict__ out, int n2) {
    const int is64 = *flag;  // uniform
    for (int i = blockIdx.x * blockDim.x + threadIdx.x; i < n2;
         i += gridDim.x * blockDim.x) {
        out[i] = is64 ? ei32[2 * i] : ei32[i];
    }
}

__global__ __launch_bounds__(256) void zero2_kernel(int* a, int na, int* b, int nb) {
    int total = na + nb;
    for (int i = blockIdx.x * blockDim.x + threadIdx.x; i < total;
         i += gridDim.x * blockDim.x) {
        if (i < na) a[i] = 0;
        else        b[i - na] = 0;
    }
}

__global__ __launch_bounds__(256) void hist_kernel(const int* __restrict__ dst, int E,
                                                   int* __restrict__ hist) {
    for (int i = blockIdx.x * blockDim.x + threadIdx.x; i < E;
         i += gridDim.x * blockDim.x) {
        atomicAdd(&hist[dst[i]], 1);
    }
}

// Block-level inclusive scan (Hillis-Steele) -> exclusive per-element + block total.
__global__ __launch_bounds__(256) void scan1_kernel(const int* __restrict__ hist,
                                                    int* __restrict__ row_start,
                                                    int* __restrict__ partial, int n) {
    __shared__ int tmp[256];
    int t = threadIdx.x;
    int i = blockIdx.x * 256 + t;
    int v = (i < n) ? hist[i] : 0;
    tmp[t] = v;
    __syncthreads();
    for (int off = 1; off < 256; off <<= 1) {
        int add = (t >= off) ? tmp[t - off] : 0;
        __syncthreads();
        tmp[t] += add;
        __syncthreads();
    }
    if (i < n) row_start[i] = tmp[t] - v;          // exclusive
    if (t == 255) partial[blockIdx.x] = tmp[255];  // block total
}

__global__ __launch_bounds__(256) void scan2_kernel(const int* __restrict__ partial,
                                                    int* __restrict__ offsets, int nb) {
    __shared__ int tmp[256];
    int t = threadIdx.x;
    int v = (t < nb) ? partial[t] : 0;
    tmp[t] = v;
    __syncthreads();
    for (int off = 1; off < 256; off <<= 1) {
        int add = (t >= off) ? tmp[t - off] : 0;
        __syncthreads();
        tmp[t] += add;
        __syncthreads();
    }
    if (t < nb) offsets[t] = tmp[t] - v;  // exclusive block offsets
}

__global__ __launch_bounds__(256) void scan3_kernel(int* __restrict__ row_start,
                                                    const int* __restrict__ offsets,
                                                    const int* __restrict__ hist,
                                                    float* __restrict__ dis,
                                                    int n, int E) {
    int i = blockIdx.x * 256 + threadIdx.x;
    if (i < n) {
        row_start[i] += offsets[i >> 8];
        dis[i] = rsqrtf((float)(hist[i] + 1));  // +1: self-loop; always > 0
    }
    if (i == 0) row_start[n] = E;
}

__global__ __launch_bounds__(256) void scatter_kernel(const int* __restrict__ src,
                                                      const int* __restrict__ dst, int E,
                                                      const int* __restrict__ row_start,
                                                      int* __restrict__ cursor,
                                                      int* __restrict__ csr_src) {
    for (int i = blockIdx.x * blockDim.x + threadIdx.x; i < E;
         i += gridDim.x * blockDim.x) {
        int d = dst[i];
        int pos = atomicAdd(&cursor[d], 1);
        csr_src[row_start[d] + pos] = src[i];
    }
}

// ---------------------------------------------------------------------------
// fp32 tiled GEMM: C[M,N] = A[M,K] * B[K,N].  No fp32 MFMA on CDNA4 -> VALU.
// Classic layout: As stored TRANSPOSED [BK][BM+4], Bs natural [BK][BN+4].
// Per kk: a[TM],b[TN] via float4 LDS reads (A conflict-free, B <=4-way),
// TM*TN FMAs -> VALU-bound. 256 threads = (BN/TN=16) x (BM/TM).
// ---------------------------------------------------------------------------
template <int BM, int BN, int TM, int TN>
__global__ __launch_bounds__(256) void gemm_tile(const float* __restrict__ A,
                                                 const float* __restrict__ B,
                                                 float* __restrict__ C,
                                                 int M, int K, int N) {
    constexpr int BK = 32;
    constexpr int TX = BN / TN;  // 16
    constexpr int TY = BM / TM;  // 16
    static_assert(TX * TY == 256, "256 threads");
    const int t = threadIdx.x;
    const int tx = t % TX;
    const int ty = t / TX;
    const int row0 = blockIdx.x * BM;

    __shared__ float As[BK][BM + 4];  // transposed A tile
    __shared__ float Bs[BK][BN + 4];

    float acc[TM][TN];
#pragma unroll
    for (int i = 0; i < TM; i++)
#pragma unroll
        for (int j = 0; j < TN; j++) acc[i][j] = 0.f;

    for (int k0 = 0; k0 < K; k0 += BK) {
        // A tile: read row-major float4, store transposed (scalar stores)
        constexpr int A4 = BM * BK / 4;
#pragma unroll
        for (int idx4 = t; idx4 < A4; idx4 += 256) {
            int r = idx4 / (BK / 4);
            int c4 = idx4 % (BK / 4);
            float4 v = make_float4(0.f, 0.f, 0.f, 0.f);
            int gr = row0 + r;
            if (gr < M) v = *(const float4*)&A[(size_t)gr * K + k0 + c4 * 4];
            As[c4 * 4 + 0][r] = v.x;
            As[c4 * 4 + 1][r] = v.y;
            As[c4 * 4 + 2][r] = v.z;
            As[c4 * 4 + 3][r] = v.w;
        }
        // B tile: natural row-major, float4 stores ((BN+4) stride keeps 16B align)
        constexpr int B4 = BK * BN / 4;
#pragma unroll
        for (int idx4 = t; idx4 < B4; idx4 += 256) {
            int r = idx4 / (BN / 4);
            int c4 = idx4 % (BN / 4);
            float4 v = *(const float4*)&B[(size_t)(k0 + r) * N + c4 * 4];
            *(float4*)&Bs[r][c4 * 4] = v;
        }
        __syncthreads();

#pragma unroll 4
        for (int kk = 0; kk < BK; kk++) {
            float a[TM], b[TN];
#pragma unroll
            for (int i = 0; i < TM; i += 4)
                *(float4*)&a[i] = *(const float4*)&As[kk][ty * TM + i];
#pragma unroll
            for (int j = 0; j < TN; j += 4)
                *(float4*)&b[j] = *(const float4*)&Bs[kk][tx * TN + j];
#pragma unroll
            for (int i = 0; i < TM; i++)
#pragma unroll
                for (int j = 0; j < TN; j++) acc[i][j] += a[i] * b[j];
        }
        __syncthreads();
    }

#pragma unroll
    for (int i = 0; i < TM; i++) {
        int gr = row0 + ty * TM + i;
        if (gr < M) {
#pragma unroll
            for (int j = 0; j < TN; j += 4) {
                float4 v = make_float4(acc[i][j], acc[i][j + 1], acc[i][j + 2],
                                       acc[i][j + 3]);
                *(float4*)&C[(size_t)gr * N + tx * TN + j] = v;
            }
        }
    }
}

// ---------------------------------------------------------------------------
// Aggregation layer 1: 128 ch, 1 wave/node, lane = 2 ch (float2). Edge loop
// unrolled x2 for load ILP. Epilogue: +b1, tanh.
// ---------------------------------------------------------------------------
__global__ __launch_bounds__(256) void agg1_kernel(const float* __restrict__ h1,
                                                   const float* __restrict__ dis,
                                                   const int* __restrict__ row_start,
                                                   const int* __restrict__ csr_src,
                                                   const float* __restrict__ b1,
                                                   float* __restrict__ hout, int n) {
    int wid = threadIdx.x >> 6;
    int lane = threadIdx.x & 63;
    int node = blockIdx.x * 4 + wid;
    if (node >= n) return;

    const float2* h1v = (const float2*)h1;
    float dd = dis[node];
    float2 acc = h1v[(size_t)node * 64 + lane];
    float sl = dd * dd;  // self-loop norm
    acc.x *= sl;
    acc.y *= sl;

    int e0 = row_start[node], e1 = row_start[node + 1];
    int e = e0;
    for (; e + 2 <= e1; e += 2) {
        int s0 = csr_src[e];
        int s1 = csr_src[e + 1];
        float n0 = dis[s0] * dd;
        float n1 = dis[s1] * dd;
        float2 v0 = h1v[(size_t)s0 * 64 + lane];
        float2 v1 = h1v[(size_t)s1 * 64 + lane];
        acc.x += v0.x * n0 + v1.x * n1;
        acc.y += v0.y * n0 + v1.y * n1;
    }
    if (e < e1) {
        int s = csr_src[e];
        float ns = dis[s] * dd;
        float2 v = h1v[(size_t)s * 64 + lane];
        acc.x += v.x * ns;
        acc.y += v.y * ns;
    }
    float2 bb = ((const float2*)b1)[lane];
    float2 o;
    o.x = tanhf(acc.x + bb.x);
    o.y = tanhf(acc.y + bb.y);
    ((float2*)hout)[(size_t)node * 64 + lane] = o;
}

// Aggregation layer 2: 64 ch, 1 wave/node, lane = 1 ch. +b2.
__global__ __launch_bounds__(256) void agg2_kernel(const float* __restrict__ h2,
                                                   const float* __restrict__ dis,
                                                   const int* __restrict__ row_start,
                                                   const int* __restrict__ csr_src,
                                                   const float* __restrict__ b2,
                                                   float* __restrict__ out, int n) {
    int wid = threadIdx.x >> 6;
    int lane = threadIdx.x & 63;
    int node = blockIdx.x * 4 + wid;
    if (node >= n) return;

    float dd = dis[node];
    float acc = h2[(size_t)node * 64 + lane] * dd * dd;

    int e0 = row_start[node], e1 = row_start[node + 1];
    int e = e0;
    for (; e + 2 <= e1; e += 2) {
        int s0 = csr_src[e];
        int s1 = csr_src[e + 1];
        float v0 = h2[(size_t)s0 * 64 + lane];
        float v1 = h2[(size_t)s1 * 64 + lane];
        acc += v0 * (dis[s0] * dd) + v1 * (dis[s1] * dd);
    }
    if (e < e1) {
        int s = csr_src[e];
        acc += h2[(size_t)s * 64 + lane] * dis[s] * dd;
    }
    out[(size_t)node * 64 + lane] = acc + b2[lane];
}

// ---------------------------------------------------------------------------
extern "C" void kernel_launch(void* const* d_in, const int* in_sizes, int n_in,
                              void* d_out, int out_size, void* d_ws, size_t ws_size,
                              hipStream_t stream) {
    const float* x  = (const float*)d_in[0];
    const int*   ei = (const int*)d_in[1];
    const float* W1 = (const float*)d_in[2];
    const float* b1 = (const float*)d_in[3];
    const float* W2 = (const float*)d_in[4];
    const float* b2 = (const float*)d_in[5];

    const int hid    = in_sizes[3];            // 128
    const int in_ch  = in_sizes[2] / hid;      // 128
    const int out_ch = in_sizes[5];            // 64
    const int N      = in_sizes[0] / in_ch;    // 50000
    const int E      = in_sizes[1] / 2;        // 800000

    // workspace carve-out (~75 MB)
    char* wsp = (char*)d_ws;
    auto alloc = [&](size_t bytes) -> char* {
        char* p = wsp;
        wsp += (bytes + 255) & ~(size_t)255;
        return p;
    };
    float* h1        = (float*)alloc((size_t)N * hid * 4);
    float* hmid      = (float*)alloc((size_t)N * hid * 4);
    float* h2        = (float*)alloc((size_t)N * out_ch * 4);
    int*   hist      = (int*)alloc((size_t)N * 4);
    int*   cursor    = (int*)alloc((size_t)N * 4);
    int*   row_start = (int*)alloc((size_t)(N + 1) * 4);
    float* dis       = (float*)alloc((size_t)N * 4);
    int*   partial   = (int*)alloc(1024);
    int*   offsets   = (int*)alloc(1024);
    int*   flag      = (int*)alloc(256);
    int*   enorm     = (int*)alloc((size_t)2 * E * 4);  // normalized int32 edges
    int*   csr_src   = (int*)alloc((size_t)E * 4);

    const int NB = (N + 255) / 256;  // 196 (must be <= 256 for scan2)

    // --- edge dtype normalization (int64 vs int32 robustness) ---
    detect_kernel<<<1, 64, 0, stream>>>(ei, flag);
    normalize_kernel<<<2048, 256, 0, stream>>>(ei, flag, enorm, 2 * E);
    const int* esrc = enorm;
    const int* edst = enorm + E;

    // --- CSR build ---
    zero2_kernel<<<256, 256, 0, stream>>>(hist, N, cursor, N);
    hist_kernel<<<1024, 256, 0, stream>>>(edst, E, hist);
    scan1_kernel<<<NB, 256, 0, stream>>>(hist, row_start, partial, N);
    scan2_kernel<<<1, 256, 0, stream>>>(partial, offsets, NB);
    scan3_kernel<<<NB, 256, 0, stream>>>(row_start, offsets, hist, dis, N, E);
    scatter_kernel<<<1024, 256, 0, stream>>>(esrc, edst, E, row_start, cursor, csr_src);

    // --- layer 1 ---
    gemm_tile<128, 128, 8, 8><<<(N + 127) / 128, 256, 0, stream>>>(x, W1, h1, N, in_ch, hid);
    agg1_kernel<<<(N + 3) / 4, 256, 0, stream>>>(h1, dis, row_start, csr_src, b1, hmid, N);

    // --- layer 2 ---
    gemm_tile<128, 64, 8, 4><<<(N + 127) / 128, 256, 0, stream>>>(hmid, W2, h2, N, hid, out_ch);
    agg2_kernel<<<(N + 3) / 4, 256, 0, stream>>>(h2, dis, row_start, csr_src, b2,
                                                 (float*)d_out, N);
}

// Round 4
// 321.341 us; speedup vs baseline: 1.0585x; 1.0585x over previous
//
#include <hip/hip_runtime.h>
#include <math.h>

// ---------------------------------------------------------------------------
// 2-layer GCN: out = A_hat( tanh( A_hat(X W1) + b1 ) ) W2 + b2
// A_hat = D^-1/2 (A + I) D^-1/2, dst-CSR built each call.
// Key factorization: h' = (X W) * dis[row] (folded into GEMM epilogue), so
// aggregation is out[d] = dis[d] * ( h'[d] + sum_{s in N(d)} h'[s] )  — the
// edge loop is pure row-load + add (no per-edge dis load / multiply).
// ---------------------------------------------------------------------------

// --- edge dtype probe: int64 layout => odd 32-bit words all zero -----------
__global__ void detect_kernel(const int* __restrict__ ei32, int* __restrict__ flag) {
    if (blockIdx.x == 0 && threadIdx.x == 0) {
        int is64 = 1;
        for (int k = 1; k < 64; k += 2)
            if (ei32[k] != 0) { is64 = 0; break; }
        *flag = is64;
    }
}

// emit clean int32 edge array regardless of input layout; also zero hist
__global__ __launch_bounds__(256) void normalize_kernel(const int* __restrict__ ei32,
                                                        const int* __restrict__ flag,
                                                        int* __restrict__ out, int n2,
                                                        int* __restrict__ hist, int nh) {
    const int is64 = *flag;  // uniform
    for (int i = blockIdx.x * blockDim.x + threadIdx.x; i < n2;
         i += gridDim.x * blockDim.x) {
        out[i] = is64 ? ei32[2 * i] : ei32[i];
        if (i < nh) hist[i] = 0;
    }
}

__global__ __launch_bounds__(256) void hist_kernel(const int* __restrict__ dst, int E,
                                                   int* __restrict__ hist) {
    for (int i = blockIdx.x * blockDim.x + threadIdx.x; i < E;
         i += gridDim.x * blockDim.x) {
        atomicAdd(&hist[dst[i]], 1);
    }
}

// Block-level inclusive scan (Hillis-Steele) -> exclusive per-element + block total.
__global__ __launch_bounds__(256) void scan1_kernel(const int* __restrict__ hist,
                                                    int* __restrict__ row_start,
                                                    int* __restrict__ partial, int n) {
    __shared__ int tmp[256];
    int t = threadIdx.x;
    int i = blockIdx.x * 256 + t;
    int v = (i < n) ? hist[i] : 0;
    tmp[t] = v;
    __syncthreads();
    for (int off = 1; off < 256; off <<= 1) {
        int add = (t >= off) ? tmp[t - off] : 0;
        __syncthreads();
        tmp[t] += add;
        __syncthreads();
    }
    if (i < n) row_start[i] = tmp[t] - v;          // exclusive
    if (t == 255) partial[blockIdx.x] = tmp[255];  // block total
}

__global__ __launch_bounds__(256) void scan2_kernel(const int* __restrict__ partial,
                                                    int* __restrict__ offsets, int nb) {
    __shared__ int tmp[256];
    int t = threadIdx.x;
    int v = (t < nb) ? partial[t] : 0;
    tmp[t] = v;
    __syncthreads();
    for (int off = 1; off < 256; off <<= 1) {
        int add = (t >= off) ? tmp[t - off] : 0;
        __syncthreads();
        tmp[t] += add;
        __syncthreads();
    }
    if (t < nb) offsets[t] = tmp[t] - v;  // exclusive block offsets
}

// finalize row_start, compute dis, zero cursor
__global__ __launch_bounds__(256) void scan3_kernel(int* __restrict__ row_start,
                                                    const int* __restrict__ offsets,
                                                    const int* __restrict__ hist,
                                                    float* __restrict__ dis,
                                                    int* __restrict__ cursor,
                                                    int n, int E) {
    int i = blockIdx.x * 256 + threadIdx.x;
    if (i < n) {
        row_start[i] += offsets[i >> 8];
        dis[i] = rsqrtf((float)(hist[i] + 1));  // +1: self-loop; always > 0
        cursor[i] = 0;
    }
    if (i == 0) row_start[n] = E;
}

__global__ __launch_bounds__(256) void scatter_kernel(const int* __restrict__ src,
                                                      const int* __restrict__ dst, int E,
                                                      const int* __restrict__ row_start,
                                                      int* __restrict__ cursor,
                                                      int* __restrict__ csr_src) {
    for (int i = blockIdx.x * blockDim.x + threadIdx.x; i < E;
         i += gridDim.x * blockDim.x) {
        int d = dst[i];
        int pos = atomicAdd(&cursor[d], 1);
        csr_src[row_start[d] + pos] = src[i];
    }
}

// ---------------------------------------------------------------------------
// fp32 tiled GEMM with row-scale epilogue: C[r,:] = (A B)[r,:] * scale[r].
// No fp32 MFMA on CDNA4 -> VALU. As stored TRANSPOSED [BK][BM+4], Bs natural.
// ---------------------------------------------------------------------------
template <int BM, int BN, int TM, int TN>
__global__ __launch_bounds__(256) void gemm_tile(const float* __restrict__ A,
                                                 const float* __restrict__ B,
                                                 const float* __restrict__ scale,
                                                 float* __restrict__ C,
                                                 int M, int K, int N) {
    constexpr int BK = 32;
    constexpr int TX = BN / TN;  // 16
    constexpr int TY = BM / TM;  // 16
    static_assert(TX * TY == 256, "256 threads");
    const int t = threadIdx.x;
    const int tx = t % TX;
    const int ty = t / TX;
    const int row0 = blockIdx.x * BM;

    __shared__ float As[BK][BM + 4];  // transposed A tile
    __shared__ float Bs[BK][BN + 4];

    float acc[TM][TN];
#pragma unroll
    for (int i = 0; i < TM; i++)
#pragma unroll
        for (int j = 0; j < TN; j++) acc[i][j] = 0.f;

    for (int k0 = 0; k0 < K; k0 += BK) {
        constexpr int A4 = BM * BK / 4;
#pragma unroll
        for (int idx4 = t; idx4 < A4; idx4 += 256) {
            int r = idx4 / (BK / 4);
            int c4 = idx4 % (BK / 4);
            float4 v = make_float4(0.f, 0.f, 0.f, 0.f);
            int gr = row0 + r;
            if (gr < M) v = *(const float4*)&A[(size_t)gr * K + k0 + c4 * 4];
            As[c4 * 4 + 0][r] = v.x;
            As[c4 * 4 + 1][r] = v.y;
            As[c4 * 4 + 2][r] = v.z;
            As[c4 * 4 + 3][r] = v.w;
        }
        constexpr int B4 = BK * BN / 4;
#pragma unroll
        for (int idx4 = t; idx4 < B4; idx4 += 256) {
            int r = idx4 / (BN / 4);
            int c4 = idx4 % (BN / 4);
            float4 v = *(const float4*)&B[(size_t)(k0 + r) * N + c4 * 4];
            *(float4*)&Bs[r][c4 * 4] = v;
        }
        __syncthreads();

#pragma unroll 4
        for (int kk = 0; kk < BK; kk++) {
            float a[TM], b[TN];
#pragma unroll
            for (int i = 0; i < TM; i += 4)
                *(float4*)&a[i] = *(const float4*)&As[kk][ty * TM + i];
#pragma unroll
            for (int j = 0; j < TN; j += 4)
                *(float4*)&b[j] = *(const float4*)&Bs[kk][tx * TN + j];
#pragma unroll
            for (int i = 0; i < TM; i++)
#pragma unroll
                for (int j = 0; j < TN; j++) acc[i][j] += a[i] * b[j];
        }
        __syncthreads();
    }

#pragma unroll
    for (int i = 0; i < TM; i++) {
        int gr = row0 + ty * TM + i;
        if (gr < M) {
            float sc = scale[gr];
#pragma unroll
            for (int j = 0; j < TN; j += 4) {
                float4 v = make_float4(acc[i][j] * sc, acc[i][j + 1] * sc,
                                       acc[i][j + 2] * sc, acc[i][j + 3] * sc);
                *(float4*)&C[(size_t)gr * N + tx * TN + j] = v;
            }
        }
    }
}

// ---------------------------------------------------------------------------
// Aggregation layer 1: 128 ch, 1 wave/node, lane = 2 ch (float2).
// hs = pre-scaled h' rows; inner loop = pure gather+add, 4-deep unroll.
// Epilogue: *dis[node], +b1, tanh.
// ---------------------------------------------------------------------------
__global__ __launch_bounds__(256) void agg1_kernel(const float* __restrict__ hs,
                                                   const float* __restrict__ dis,
                                                   const int* __restrict__ row_start,
                                                   const int* __restrict__ csr_src,
                                                   const float* __restrict__ b1,
                                                   float* __restrict__ hout, int n) {
    int wid = threadIdx.x >> 6;
    int lane = threadIdx.x & 63;
    int node = blockIdx.x * 4 + wid;
    if (node >= n) return;

    const float2* hv = (const float2*)hs;
    float2 acc = hv[(size_t)node * 64 + lane];  // self-loop term (pre-scaled)

    int e0 = row_start[node], e1 = row_start[node + 1];
    int e = e0;
    for (; e + 4 <= e1; e += 4) {
        int s0 = csr_src[e + 0];
        int s1 = csr_src[e + 1];
        int s2 = csr_src[e + 2];
        int s3 = csr_src[e + 3];
        float2 v0 = hv[(size_t)s0 * 64 + lane];
        float2 v1 = hv[(size_t)s1 * 64 + lane];
        float2 v2 = hv[(size_t)s2 * 64 + lane];
        float2 v3 = hv[(size_t)s3 * 64 + lane];
        acc.x += (v0.x + v1.x) + (v2.x + v3.x);
        acc.y += (v0.y + v1.y) + (v2.y + v3.y);
    }
    for (; e < e1; ++e) {
        int s = csr_src[e];
        float2 v = hv[(size_t)s * 64 + lane];
        acc.x += v.x;
        acc.y += v.y;
    }
    float dd = dis[node];
    float2 bb = ((const float2*)b1)[lane];
    float2 o;
    o.x = tanhf(acc.x * dd + bb.x);
    o.y = tanhf(acc.y * dd + bb.y);
    ((float2*)hout)[(size_t)node * 64 + lane] = o;
}

// Aggregation layer 2: 64 ch, 1 wave/node, lane = 1 ch. 4-deep unroll. +b2.
__global__ __launch_bounds__(256) void agg2_kernel(const float* __restrict__ hs,
                                                   const float* __restrict__ dis,
                                                   const int* __restrict__ row_start,
                                                   const int* __restrict__ csr_src,
                                                   const float* __restrict__ b2,
                                                   float* __restrict__ out, int n) {
    int wid = threadIdx.x >> 6;
    int lane = threadIdx.x & 63;
    int node = blockIdx.x * 4 + wid;
    if (node >= n) return;

    float acc = hs[(size_t)node * 64 + lane];  // self-loop term (pre-scaled)

    int e0 = row_start[node], e1 = row_start[node + 1];
    int e = e0;
    for (; e + 4 <= e1; e += 4) {
        int s0 = csr_src[e + 0];
        int s1 = csr_src[e + 1];
        int s2 = csr_src[e + 2];
        int s3 = csr_src[e + 3];
        float v0 = hs[(size_t)s0 * 64 + lane];
        float v1 = hs[(size_t)s1 * 64 + lane];
        float v2 = hs[(size_t)s2 * 64 + lane];
        float v3 = hs[(size_t)s3 * 64 + lane];
        acc += (v0 + v1) + (v2 + v3);
    }
    for (; e < e1; ++e) {
        acc += hs[(size_t)csr_src[e] * 64 + lane];
    }
    out[(size_t)node * 64 + lane] = acc * dis[node] + b2[lane];
}

// ---------------------------------------------------------------------------
extern "C" void kernel_launch(void* const* d_in, const int* in_sizes, int n_in,
                              void* d_out, int out_size, void* d_ws, size_t ws_size,
                              hipStream_t stream) {
    const float* x  = (const float*)d_in[0];
    const int*   ei = (const int*)d_in[1];
    const float* W1 = (const float*)d_in[2];
    const float* b1 = (const float*)d_in[3];
    const float* W2 = (const float*)d_in[4];
    const float* b2 = (const float*)d_in[5];

    const int hid    = in_sizes[3];            // 128
    const int in_ch  = in_sizes[2] / hid;      // 128
    const int out_ch = in_sizes[5];            // 64
    const int N      = in_sizes[0] / in_ch;    // 50000
    const int E      = in_sizes[1] / 2;        // 800000

    // workspace carve-out (~75 MB)
    char* wsp = (char*)d_ws;
    auto alloc = [&](size_t bytes) -> char* {
        char* p = wsp;
        wsp += (bytes + 255) & ~(size_t)255;
        return p;
    };
    float* h1        = (float*)alloc((size_t)N * hid * 4);     // pre-scaled h1'
    float* hmid      = (float*)alloc((size_t)N * hid * 4);
    float* h2        = (float*)alloc((size_t)N * out_ch * 4);  // pre-scaled h2'
    int*   hist      = (int*)alloc((size_t)N * 4);
    int*   cursor    = (int*)alloc((size_t)N * 4);
    int*   row_start = (int*)alloc((size_t)(N + 1) * 4);
    float* dis       = (float*)alloc((size_t)N * 4);
    int*   partial   = (int*)alloc(1024);
    int*   offsets   = (int*)alloc(1024);
    int*   flag      = (int*)alloc(256);
    int*   enorm     = (int*)alloc((size_t)2 * E * 4);  // normalized int32 edges
    int*   csr_src   = (int*)alloc((size_t)E * 4);

    const int NB = (N + 255) / 256;  // 196 (must be <= 256 for scan2)

    // --- edge dtype normalization + hist zero ---
    detect_kernel<<<1, 64, 0, stream>>>(ei, flag);
    normalize_kernel<<<2048, 256, 0, stream>>>(ei, flag, enorm, 2 * E, hist, N);
    const int* esrc = enorm;
    const int* edst = enorm + E;

    // --- CSR build ---
    hist_kernel<<<1024, 256, 0, stream>>>(edst, E, hist);
    scan1_kernel<<<NB, 256, 0, stream>>>(hist, row_start, partial, N);
    scan2_kernel<<<1, 256, 0, stream>>>(partial, offsets, NB);
    scan3_kernel<<<NB, 256, 0, stream>>>(row_start, offsets, hist, dis, cursor, N, E);
    scatter_kernel<<<1024, 256, 0, stream>>>(esrc, edst, E, row_start, cursor, csr_src);

    // --- layer 1 ---
    gemm_tile<128, 128, 8, 8><<<(N + 127) / 128, 256, 0, stream>>>(x, W1, dis, h1, N, in_ch, hid);
    agg1_kernel<<<(N + 3) / 4, 256, 0, stream>>>(h1, dis, row_start, csr_src, b1, hmid, N);

    // --- layer 2 ---
    gemm_tile<128, 64, 8, 4><<<(N + 127) / 128, 256, 0, stream>>>(hmid, W2, dis, h2, N, hid, out_ch);
    agg2_kernel<<<(N + 3) / 4, 256, 0, stream>>>(h2, dis, row_start, csr_src, b2,
                                                 (float*)d_out, N);
}

// Round 5
// 314.950 us; speedup vs baseline: 1.0800x; 1.0203x over previous
//
#include <hip/hip_runtime.h>
#include <hip/hip_fp16.h>
#include <math.h>

// ---------------------------------------------------------------------------
// 2-layer GCN: out = A_hat( tanh( A_hat(X W1) + b1 ) ) W2 + b2
// A_hat = D^-1/2 (A + I) D^-1/2, dst-CSR built each call.
// h' = (X W) * dis[row] folded into GEMM epilogue; agg loop = pure gather+add.
// The two GATHERED tensors (h1', h2') are stored fp16 (halves cache-line
// traffic + footprint); all streamed tensors stay fp32; accumulation fp32.
// ---------------------------------------------------------------------------

// emit clean int32 edge array regardless of int64/int32 input layout; zero hist.
// int64 layout <=> odd 32-bit words of the edge buffer are all zero (ids < 50000).
__global__ __launch_bounds__(256) void normalize_kernel(const int* __restrict__ ei32,
                                                        int* __restrict__ out, int n2,
                                                        int* __restrict__ hist, int nh) {
    __shared__ int s_is64;
    if (threadIdx.x == 0) {
        int is64 = 1;
        for (int k = 1; k < 64; k += 2)
            if (ei32[k] != 0) { is64 = 0; break; }
        s_is64 = is64;
    }
    __syncthreads();
    const int is64 = s_is64;
    for (int i = blockIdx.x * blockDim.x + threadIdx.x; i < n2;
         i += gridDim.x * blockDim.x) {
        out[i] = is64 ? ei32[2 * i] : ei32[i];
        if (i < nh) hist[i] = 0;
    }
}

__global__ __launch_bounds__(256) void hist_kernel(const int* __restrict__ dst, int E,
                                                   int* __restrict__ hist) {
    for (int i = blockIdx.x * blockDim.x + threadIdx.x; i < E;
         i += gridDim.x * blockDim.x) {
        atomicAdd(&hist[dst[i]], 1);
    }
}

// Block-level inclusive scan (Hillis-Steele) -> exclusive per-element + block total.
__global__ __launch_bounds__(256) void scan1_kernel(const int* __restrict__ hist,
                                                    int* __restrict__ row_start,
                                                    int* __restrict__ partial, int n) {
    __shared__ int tmp[256];
    int t = threadIdx.x;
    int i = blockIdx.x * 256 + t;
    int v = (i < n) ? hist[i] : 0;
    tmp[t] = v;
    __syncthreads();
    for (int off = 1; off < 256; off <<= 1) {
        int add = (t >= off) ? tmp[t - off] : 0;
        __syncthreads();
        tmp[t] += add;
        __syncthreads();
    }
    if (i < n) row_start[i] = tmp[t] - v;          // exclusive
    if (t == 255) partial[blockIdx.x] = tmp[255];  // block total
}

__global__ __launch_bounds__(256) void scan2_kernel(const int* __restrict__ partial,
                                                    int* __restrict__ offsets, int nb) {
    __shared__ int tmp[256];
    int t = threadIdx.x;
    int v = (t < nb) ? partial[t] : 0;
    tmp[t] = v;
    __syncthreads();
    for (int off = 1; off < 256; off <<= 1) {
        int add = (t >= off) ? tmp[t - off] : 0;
        __syncthreads();
        tmp[t] += add;
        __syncthreads();
    }
    if (t < nb) offsets[t] = tmp[t] - v;  // exclusive block offsets
}

// finalize row_start, compute dis, zero cursor
__global__ __launch_bounds__(256) void scan3_kernel(int* __restrict__ row_start,
                                                    const int* __restrict__ offsets,
                                                    const int* __restrict__ hist,
                                                    float* __restrict__ dis,
                                                    int* __restrict__ cursor,
                                                    int n, int E) {
    int i = blockIdx.x * 256 + threadIdx.x;
    if (i < n) {
        row_start[i] += offsets[i >> 8];
        dis[i] = rsqrtf((float)(hist[i] + 1));  // +1: self-loop; always > 0
        cursor[i] = 0;
    }
    if (i == 0) row_start[n] = E;
}

__global__ __launch_bounds__(256) void scatter_kernel(const int* __restrict__ src,
                                                      const int* __restrict__ dst, int E,
                                                      const int* __restrict__ row_start,
                                                      int* __restrict__ cursor,
                                                      int* __restrict__ csr_src) {
    for (int i = blockIdx.x * blockDim.x + threadIdx.x; i < E;
         i += gridDim.x * blockDim.x) {
        int d = dst[i];
        int pos = atomicAdd(&cursor[d], 1);
        csr_src[row_start[d] + pos] = src[i];
    }
}

// ---------------------------------------------------------------------------
// fp32 tiled GEMM with row-scale epilogue: C[r,:] = (A B)[r,:] * scale[r].
// HALF_OUT: cast the scaled result to fp16 (packed stores).
// No fp32 MFMA on CDNA4 -> VALU. As stored TRANSPOSED [BK][BM+4], Bs natural.
// ---------------------------------------------------------------------------
template <int BM, int BN, int TM, int TN, bool HALF_OUT>
__global__ __launch_bounds__(256) void gemm_tile(const float* __restrict__ A,
                                                 const float* __restrict__ B,
                                                 const float* __restrict__ scale,
                                                 void* __restrict__ Cv,
                                                 int M, int K, int N) {
    constexpr int BK = 32;
    constexpr int TX = BN / TN;  // 16
    constexpr int TY = BM / TM;  // 16
    static_assert(TX * TY == 256, "256 threads");
    const int t = threadIdx.x;
    const int tx = t % TX;
    const int ty = t / TX;
    const int row0 = blockIdx.x * BM;

    __shared__ float As[BK][BM + 4];  // transposed A tile
    __shared__ float Bs[BK][BN + 4];

    float acc[TM][TN];
#pragma unroll
    for (int i = 0; i < TM; i++)
#pragma unroll
        for (int j = 0; j < TN; j++) acc[i][j] = 0.f;

    for (int k0 = 0; k0 < K; k0 += BK) {
        constexpr int A4 = BM * BK / 4;
#pragma unroll
        for (int idx4 = t; idx4 < A4; idx4 += 256) {
            int r = idx4 / (BK / 4);
            int c4 = idx4 % (BK / 4);
            float4 v = make_float4(0.f, 0.f, 0.f, 0.f);
            int gr = row0 + r;
            if (gr < M) v = *(const float4*)&A[(size_t)gr * K + k0 + c4 * 4];
            As[c4 * 4 + 0][r] = v.x;
            As[c4 * 4 + 1][r] = v.y;
            As[c4 * 4 + 2][r] = v.z;
            As[c4 * 4 + 3][r] = v.w;
        }
        constexpr int B4 = BK * BN / 4;
#pragma unroll
        for (int idx4 = t; idx4 < B4; idx4 += 256) {
            int r = idx4 / (BN / 4);
            int c4 = idx4 % (BN / 4);
            float4 v = *(const float4*)&B[(size_t)(k0 + r) * N + c4 * 4];
            *(float4*)&Bs[r][c4 * 4] = v;
        }
        __syncthreads();

#pragma unroll 4
        for (int kk = 0; kk < BK; kk++) {
            float a[TM], b[TN];
#pragma unroll
            for (int i = 0; i < TM; i += 4)
                *(float4*)&a[i] = *(const float4*)&As[kk][ty * TM + i];
#pragma unroll
            for (int j = 0; j < TN; j += 4)
                *(float4*)&b[j] = *(const float4*)&Bs[kk][tx * TN + j];
#pragma unroll
            for (int i = 0; i < TM; i++)
#pragma unroll
                for (int j = 0; j < TN; j++) acc[i][j] += a[i] * b[j];
        }
        __syncthreads();
    }

#pragma unroll
    for (int i = 0; i < TM; i++) {
        int gr = row0 + ty * TM + i;
        if (gr < M) {
            float sc = scale[gr];
            if constexpr (HALF_OUT) {
                __half* C = (__half*)Cv;
                __half2 tmp[TN / 2];
#pragma unroll
                for (int j = 0; j < TN; j += 2)
                    tmp[j / 2] = __floats2half2_rn(acc[i][j] * sc, acc[i][j + 1] * sc);
                if constexpr (TN == 8) {
                    *(float4*)&C[(size_t)gr * N + tx * TN] = *(float4*)tmp;  // 16B
                } else {
                    *(float2*)&C[(size_t)gr * N + tx * TN] = *(float2*)tmp;  // 8B
                }
            } else {
                float* C = (float*)Cv;
#pragma unroll
                for (int j = 0; j < TN; j += 4) {
                    float4 v = make_float4(acc[i][j] * sc, acc[i][j + 1] * sc,
                                           acc[i][j + 2] * sc, acc[i][j + 3] * sc);
                    *(float4*)&C[(size_t)gr * N + tx * TN + j] = v;
                }
            }
        }
    }
}

// ---------------------------------------------------------------------------
// Aggregation layer 1: 128 ch, 1 wave/node, lane = 2 ch (__half2 load, fp32 acc).
// Grid-stride over nodes (persistent blocks). Epilogue: *dis, +b1, tanh -> fp32.
// ---------------------------------------------------------------------------
__global__ __launch_bounds__(256) void agg1_kernel(const __half* __restrict__ hs,
                                                   const float* __restrict__ dis,
                                                   const int* __restrict__ row_start,
                                                   const int* __restrict__ csr_src,
                                                   const float* __restrict__ b1,
                                                   float* __restrict__ hout, int n) {
    const int wid = threadIdx.x >> 6;
    const int lane = threadIdx.x & 63;
    const __half2* hv = (const __half2*)hs;

    for (int node = blockIdx.x * 4 + wid; node < n; node += gridDim.x * 4) {
        float2 acc = __half22float2(hv[(size_t)node * 64 + lane]);  // self-loop term

        int e0 = row_start[node], e1 = row_start[node + 1];
        int e = e0;
        for (; e + 4 <= e1; e += 4) {
            int s0 = csr_src[e + 0];
            int s1 = csr_src[e + 1];
            int s2 = csr_src[e + 2];
            int s3 = csr_src[e + 3];
            float2 v0 = __half22float2(hv[(size_t)s0 * 64 + lane]);
            float2 v1 = __half22float2(hv[(size_t)s1 * 64 + lane]);
            float2 v2 = __half22float2(hv[(size_t)s2 * 64 + lane]);
            float2 v3 = __half22float2(hv[(size_t)s3 * 64 + lane]);
            acc.x += (v0.x + v1.x) + (v2.x + v3.x);
            acc.y += (v0.y + v1.y) + (v2.y + v3.y);
        }
        for (; e < e1; ++e) {
            float2 v = __half22float2(hv[(size_t)csr_src[e] * 64 + lane]);
            acc.x += v.x;
            acc.y += v.y;
        }
        float dd = dis[node];
        float2 bb = ((const float2*)b1)[lane];
        float2 o;
        o.x = tanhf(acc.x * dd + bb.x);
        o.y = tanhf(acc.y * dd + bb.y);
        ((float2*)hout)[(size_t)node * 64 + lane] = o;
    }
}

// Aggregation layer 2: 64 ch, 1 wave/node, lane = 1 ch (fp16 load, fp32 acc). +b2.
__global__ __launch_bounds__(256) void agg2_kernel(const __half* __restrict__ hs,
                                                   const float* __restrict__ dis,
                                                   const int* __restrict__ row_start,
                                                   const int* __restrict__ csr_src,
                                                   const float* __restrict__ b2,
                                                   float* __restrict__ out, int n) {
    const int wid = threadIdx.x >> 6;
    const int lane = threadIdx.x & 63;

    for (int node = blockIdx.x * 4 + wid; node < n; node += gridDim.x * 4) {
        float acc = __half2float(hs[(size_t)node * 64 + lane]);  // self-loop term

        int e0 = row_start[node], e1 = row_start[node + 1];
        int e = e0;
        for (; e + 4 <= e1; e += 4) {
            int s0 = csr_src[e + 0];
            int s1 = csr_src[e + 1];
            int s2 = csr_src[e + 2];
            int s3 = csr_src[e + 3];
            float v0 = __half2float(hs[(size_t)s0 * 64 + lane]);
            float v1 = __half2float(hs[(size_t)s1 * 64 + lane]);
            float v2 = __half2float(hs[(size_t)s2 * 64 + lane]);
            float v3 = __half2float(hs[(size_t)s3 * 64 + lane]);
            acc += (v0 + v1) + (v2 + v3);
        }
        for (; e < e1; ++e) {
            acc += __half2float(hs[(size_t)csr_src[e] * 64 + lane]);
        }
        out[(size_t)node * 64 + lane] = acc * dis[node] + b2[lane];
    }
}

// ---------------------------------------------------------------------------
extern "C" void kernel_launch(void* const* d_in, const int* in_sizes, int n_in,
                              void* d_out, int out_size, void* d_ws, size_t ws_size,
                              hipStream_t stream) {
    const float* x  = (const float*)d_in[0];
    const int*   ei = (const int*)d_in[1];
    const float* W1 = (const float*)d_in[2];
    const float* b1 = (const float*)d_in[3];
    const float* W2 = (const float*)d_in[4];
    const float* b2 = (const float*)d_in[5];

    const int hid    = in_sizes[3];            // 128
    const int in_ch  = in_sizes[2] / hid;      // 128
    const int out_ch = in_sizes[5];            // 64
    const int N      = in_sizes[0] / in_ch;    // 50000
    const int E      = in_sizes[1] / 2;        // 800000

    // workspace carve-out
    char* wsp = (char*)d_ws;
    auto alloc = [&](size_t bytes) -> char* {
        char* p = wsp;
        wsp += (bytes + 255) & ~(size_t)255;
        return p;
    };
    __half* h1       = (__half*)alloc((size_t)N * hid * 2);     // fp16, gathered by agg1
    float*  hmid     = (float*)alloc((size_t)N * hid * 4);      // fp32, streamed by gemm2
    __half* h2       = (__half*)alloc((size_t)N * out_ch * 2);  // fp16, gathered by agg2
    int*   hist      = (int*)alloc((size_t)N * 4);
    int*   cursor    = (int*)alloc((size_t)N * 4);
    int*   row_start = (int*)alloc((size_t)(N + 1) * 4);
    float* dis       = (float*)alloc((size_t)N * 4);
    int*   partial   = (int*)alloc(1024);
    int*   offsets   = (int*)alloc(1024);
    int*   enorm     = (int*)alloc((size_t)2 * E * 4);  // normalized int32 edges
    int*   csr_src   = (int*)alloc((size_t)E * 4);

    const int NB = (N + 255) / 256;  // 196 (must be <= 256 for scan2)

    // --- edge dtype normalization + hist zero ---
    normalize_kernel<<<2048, 256, 0, stream>>>(ei, enorm, 2 * E, hist, N);
    const int* esrc = enorm;
    const int* edst = enorm + E;

    // --- CSR build ---
    hist_kernel<<<1024, 256, 0, stream>>>(edst, E, hist);
    scan1_kernel<<<NB, 256, 0, stream>>>(hist, row_start, partial, N);
    scan2_kernel<<<1, 256, 0, stream>>>(partial, offsets, NB);
    scan3_kernel<<<NB, 256, 0, stream>>>(row_start, offsets, hist, dis, cursor, N, E);
    scatter_kernel<<<1024, 256, 0, stream>>>(esrc, edst, E, row_start, cursor, csr_src);

    // --- layer 1 ---
    gemm_tile<128, 128, 8, 8, true><<<(N + 127) / 128, 256, 0, stream>>>(
        x, W1, dis, h1, N, in_ch, hid);
    agg1_kernel<<<1280, 256, 0, stream>>>(h1, dis, row_start, csr_src, b1, hmid, N);

    // --- layer 2 ---
    gemm_tile<128, 64, 8, 4, true><<<(N + 127) / 128, 256, 0, stream>>>(
        hmid, W2, dis, h2, N, hid, out_ch);
    agg2_kernel<<<1280, 256, 0, stream>>>(h2, dis, row_start, csr_src, b2,
                                          (float*)d_out, N);
}

// Round 8
// 275.695 us; speedup vs baseline: 1.2338x; 1.1424x over previous
//
#include <hip/hip_runtime.h>
#include <hip/hip_fp16.h>
#include <math.h>

// ---------------------------------------------------------------------------
// 2-layer GCN: out = A_hat( tanh( A_hat(X W1) + b1 ) ) W2 + b2
// A_hat = D^-1/2 (A + I) D^-1/2, dst-CSR built each call.
// h' = (X W) * dis[row] folded into GEMM epilogue; agg loop = pure gather+add.
// Gathered tensors (h1', h2') stored fp16; accumulation fp32.
// Agg kernels: per-node wave, indices vector-loaded once per 64 edges and
// broadcast via __shfl -> 8 independent row-gathers in flight (MLP attack).
// ---------------------------------------------------------------------------

// emit clean int32 edge array regardless of int64/int32 input layout; zero hist.
__global__ __launch_bounds__(256) void normalize_kernel(const int* __restrict__ ei32,
                                                        int* __restrict__ out, int n2,
                                                        int* __restrict__ hist, int nh) {
    __shared__ int s_is64;
    if (threadIdx.x == 0) {
        int is64 = 1;
        for (int k = 1; k < 64; k += 2)
            if (ei32[k] != 0) { is64 = 0; break; }
        s_is64 = is64;
    }
    __syncthreads();
    const int is64 = s_is64;
    for (int i = blockIdx.x * blockDim.x + threadIdx.x; i < n2;
         i += gridDim.x * blockDim.x) {
        out[i] = is64 ? ei32[2 * i] : ei32[i];
        if (i < nh) hist[i] = 0;
    }
}

__global__ __launch_bounds__(256) void hist_kernel(const int* __restrict__ dst, int E,
                                                   int* __restrict__ hist) {
    for (int i = blockIdx.x * blockDim.x + threadIdx.x; i < E;
         i += gridDim.x * blockDim.x) {
        atomicAdd(&hist[dst[i]], 1);
    }
}

// Block-level inclusive scan -> exclusive per-element + block total.
__global__ __launch_bounds__(256) void scan1_kernel(const int* __restrict__ hist,
                                                    int* __restrict__ row_start,
                                                    int* __restrict__ partial, int n) {
    __shared__ int tmp[256];
    int t = threadIdx.x;
    int i = blockIdx.x * 256 + t;
    int v = (i < n) ? hist[i] : 0;
    tmp[t] = v;
    __syncthreads();
    for (int off = 1; off < 256; off <<= 1) {
        int add = (t >= off) ? tmp[t - off] : 0;
        __syncthreads();
        tmp[t] += add;
        __syncthreads();
    }
    if (i < n) row_start[i] = tmp[t] - v;          // exclusive
    if (t == 255) partial[blockIdx.x] = tmp[255];  // block total
}

// Merged scan2+scan3: every block redundantly scans the <=256 block-partials,
// then finalizes row_start, dis, cursor.
__global__ __launch_bounds__(256) void scan23_kernel(int* __restrict__ row_start,
                                                     const int* __restrict__ partial,
                                                     const int* __restrict__ hist,
                                                     float* __restrict__ dis,
                                                     int* __restrict__ cursor,
                                                     int n, int E, int nb) {
    __shared__ int offs[256];
    int t = threadIdx.x;
    int v = (t < nb) ? partial[t] : 0;
    offs[t] = v;
    __syncthreads();
    for (int off = 1; off < 256; off <<= 1) {
        int add = (t >= off) ? offs[t - off] : 0;
        __syncthreads();
        offs[t] += add;
        __syncthreads();
    }
    int incl = offs[t];
    __syncthreads();
    offs[t] = incl - v;  // exclusive block offsets
    __syncthreads();

    int i = blockIdx.x * 256 + t;
    if (i < n) {
        row_start[i] += offs[i >> 8];
        dis[i] = rsqrtf((float)(hist[i] + 1));  // +1: self-loop; always > 0
        cursor[i] = 0;
    }
    if (i == 0) row_start[n] = E;
}

__global__ __launch_bounds__(256) void scatter_kernel(const int* __restrict__ src,
                                                      const int* __restrict__ dst, int E,
                                                      const int* __restrict__ row_start,
                                                      int* __restrict__ cursor,
                                                      int* __restrict__ csr_src) {
    for (int i = blockIdx.x * blockDim.x + threadIdx.x; i < E;
         i += gridDim.x * blockDim.x) {
        int d = dst[i];
        int pos = atomicAdd(&cursor[d], 1);
        csr_src[row_start[d] + pos] = src[i];
    }
}

// ---------------------------------------------------------------------------
// fp32 tiled GEMM with row-scale epilogue: C[r,:] = (A B)[r,:] * scale[r].
// HALF_OUT: cast result to fp16 (packed stores). No fp32 MFMA -> VALU.
// ---------------------------------------------------------------------------
template <int BM, int BN, int TM, int TN, bool HALF_OUT>
__global__ __launch_bounds__(256) void gemm_tile(const float* __restrict__ A,
                                                 const float* __restrict__ B,
                                                 const float* __restrict__ scale,
                                                 void* __restrict__ Cv,
                                                 int M, int K, int N) {
    constexpr int BK = 32;
    constexpr int TX = BN / TN;  // 16
    constexpr int TY = BM / TM;  // 16
    static_assert(TX * TY == 256, "256 threads");
    const int t = threadIdx.x;
    const int tx = t % TX;
    const int ty = t / TX;
    const int row0 = blockIdx.x * BM;

    __shared__ float As[BK][BM + 4];  // transposed A tile
    __shared__ float Bs[BK][BN + 4];

    float acc[TM][TN];
#pragma unroll
    for (int i = 0; i < TM; i++)
#pragma unroll
        for (int j = 0; j < TN; j++) acc[i][j] = 0.f;

    for (int k0 = 0; k0 < K; k0 += BK) {
        constexpr int A4 = BM * BK / 4;
#pragma unroll
        for (int idx4 = t; idx4 < A4; idx4 += 256) {
            int r = idx4 / (BK / 4);
            int c4 = idx4 % (BK / 4);
            float4 v = make_float4(0.f, 0.f, 0.f, 0.f);
            int gr = row0 + r;
            if (gr < M) v = *(const float4*)&A[(size_t)gr * K + k0 + c4 * 4];
            As[c4 * 4 + 0][r] = v.x;
            As[c4 * 4 + 1][r] = v.y;
            As[c4 * 4 + 2][r] = v.z;
            As[c4 * 4 + 3][r] = v.w;
        }
        constexpr int B4 = BK * BN / 4;
#pragma unroll
        for (int idx4 = t; idx4 < B4; idx4 += 256) {
            int r = idx4 / (BN / 4);
            int c4 = idx4 % (BN / 4);
            float4 v = *(const float4*)&B[(size_t)(k0 + r) * N + c4 * 4];
            *(float4*)&Bs[r][c4 * 4] = v;
        }
        __syncthreads();

#pragma unroll 4
        for (int kk = 0; kk < BK; kk++) {
            float a[TM], b[TN];
#pragma unroll
            for (int i = 0; i < TM; i += 4)
                *(float4*)&a[i] = *(const float4*)&As[kk][ty * TM + i];
#pragma unroll
            for (int j = 0; j < TN; j += 4)
                *(float4*)&b[j] = *(const float4*)&Bs[kk][tx * TN + j];
#pragma unroll
            for (int i = 0; i < TM; i++)
#pragma unroll
                for (int j = 0; j < TN; j++) acc[i][j] += a[i] * b[j];
        }
        __syncthreads();
    }

#pragma unroll
    for (int i = 0; i < TM; i++) {
        int gr = row0 + ty * TM + i;
        if (gr < M) {
            float sc = scale[gr];
            if constexpr (HALF_OUT) {
                __half* C = (__half*)Cv;
                __half2 tmp[TN / 2];
#pragma unroll
                for (int j = 0; j < TN; j += 2)
                    tmp[j / 2] = __floats2half2_rn(acc[i][j] * sc, acc[i][j + 1] * sc);
                if constexpr (TN == 8) {
                    *(float4*)&C[(size_t)gr * N + tx * TN] = *(float4*)tmp;  // 16B
                } else {
                    *(float2*)&C[(size_t)gr * N + tx * TN] = *(float2*)tmp;  // 8B
                }
            } else {
                float* C = (float*)Cv;
#pragma unroll
                for (int j = 0; j < TN; j += 4) {
                    float4 v = make_float4(acc[i][j] * sc, acc[i][j + 1] * sc,
                                           acc[i][j + 2] * sc, acc[i][j + 3] * sc);
                    *(float4*)&C[(size_t)gr * N + tx * TN + j] = v;
                }
            }
        }
    }
}

// ---------------------------------------------------------------------------
// Aggregation layer 1: 128 ch, 1 wave/node, lane = 2 ch (__half2, fp32 acc).
// Indices vector-loaded (<=64/iter), broadcast via __shfl; 8 gathers in flight.
// ---------------------------------------------------------------------------
__global__ __launch_bounds__(256) void agg1_kernel(const __half* __restrict__ hs,
                                                   const float* __restrict__ dis,
                                                   const int* __restrict__ row_start,
                                                   const int* __restrict__ csr_src,
                                                   const float* __restrict__ b1,
                                                   float* __restrict__ hout, int n) {
    const int wid = threadIdx.x >> 6;
    const int lane = threadIdx.x & 63;
    const __half2* hv = (const __half2*)hs;

    for (int node = blockIdx.x * 4 + wid; node < n; node += gridDim.x * 4) {
        float2 acc = __half22float2(hv[(size_t)node * 64 + lane]);  // self-loop term

        const int e0 = row_start[node];
        const int deg = row_start[node + 1] - e0;

        for (int base = 0; base < deg; base += 64) {
            const int cnt = min(64, deg - base);
            int myidx = 0;
            if (lane < cnt) myidx = csr_src[e0 + base + lane];

            int k = 0;
            for (; k + 8 <= cnt; k += 8) {
                int s0 = __shfl(myidx, k + 0);
                int s1 = __shfl(myidx, k + 1);
                int s2 = __shfl(myidx, k + 2);
                int s3 = __shfl(myidx, k + 3);
                int s4 = __shfl(myidx, k + 4);
                int s5 = __shfl(myidx, k + 5);
                int s6 = __shfl(myidx, k + 6);
                int s7 = __shfl(myidx, k + 7);
                float2 v0 = __half22float2(hv[(size_t)s0 * 64 + lane]);
                float2 v1 = __half22float2(hv[(size_t)s1 * 64 + lane]);
                float2 v2 = __half22float2(hv[(size_t)s2 * 64 + lane]);
                float2 v3 = __half22float2(hv[(size_t)s3 * 64 + lane]);
                float2 v4 = __half22float2(hv[(size_t)s4 * 64 + lane]);
                float2 v5 = __half22float2(hv[(size_t)s5 * 64 + lane]);
                float2 v6 = __half22float2(hv[(size_t)s6 * 64 + lane]);
                float2 v7 = __half22float2(hv[(size_t)s7 * 64 + lane]);
                acc.x += ((v0.x + v1.x) + (v2.x + v3.x)) + ((v4.x + v5.x) + (v6.x + v7.x));
                acc.y += ((v0.y + v1.y) + (v2.y + v3.y)) + ((v4.y + v5.y) + (v6.y + v7.y));
            }
            for (; k < cnt; ++k) {
                int s = __shfl(myidx, k);
                float2 v = __half22float2(hv[(size_t)s * 64 + lane]);
                acc.x += v.x;
                acc.y += v.y;
            }
        }
        float dd = dis[node];
        float2 bb = ((const float2*)b1)[lane];
        float2 o;
        o.x = tanhf(acc.x * dd + bb.x);
        o.y = tanhf(acc.y * dd + bb.y);
        ((float2*)hout)[(size_t)node * 64 + lane] = o;
    }
}

// Aggregation layer 2: 64 ch, 1 wave/node, lane = 1 ch (fp16, fp32 acc). +b2.
__global__ __launch_bounds__(256) void agg2_kernel(const __half* __restrict__ hs,
                                                   const float* __restrict__ dis,
                                                   const int* __restrict__ row_start,
                                                   const int* __restrict__ csr_src,
                                                   const float* __restrict__ b2,
                                                   float* __restrict__ out, int n) {
    const int wid = threadIdx.x >> 6;
    const int lane = threadIdx.x & 63;

    for (int node = blockIdx.x * 4 + wid; node < n; node += gridDim.x * 4) {
        float acc = __half2float(hs[(size_t)node * 64 + lane]);  // self-loop term

        const int e0 = row_start[node];
        const int deg = row_start[node + 1] - e0;

        for (int base = 0; base < deg; base += 64) {
            const int cnt = min(64, deg - base);
            int myidx = 0;
            if (lane < cnt) myidx = csr_src[e0 + base + lane];

            int k = 0;
            for (; k + 8 <= cnt; k += 8) {
                int s0 = __shfl(myidx, k + 0);
                int s1 = __shfl(myidx, k + 1);
                int s2 = __shfl(myidx, k + 2);
                int s3 = __shfl(myidx, k + 3);
                int s4 = __shfl(myidx, k + 4);
                int s5 = __shfl(myidx, k + 5);
                int s6 = __shfl(myidx, k + 6);
                int s7 = __shfl(myidx, k + 7);
                float v0 = __half2float(hs[(size_t)s0 * 64 + lane]);
                float v1 = __half2float(hs[(size_t)s1 * 64 + lane]);
                float v2 = __half2float(hs[(size_t)s2 * 64 + lane]);
                float v3 = __half2float(hs[(size_t)s3 * 64 + lane]);
                float v4 = __half2float(hs[(size_t)s4 * 64 + lane]);
                float v5 = __half2float(hs[(size_t)s5 * 64 + lane]);
                float v6 = __half2float(hs[(size_t)s6 * 64 + lane]);
                float v7 = __half2float(hs[(size_t)s7 * 64 + lane]);
                acc += ((v0 + v1) + (v2 + v3)) + ((v4 + v5) + (v6 + v7));
            }
            for (; k < cnt; ++k) {
                int s = __shfl(myidx, k);
                acc += __half2float(hs[(size_t)s * 64 + lane]);
            }
        }
        out[(size_t)node * 64 + lane] = acc * dis[node] + b2[lane];
    }
}

// ---------------------------------------------------------------------------
extern "C" void kernel_launch(void* const* d_in, const int* in_sizes, int n_in,
                              void* d_out, int out_size, void* d_ws, size_t ws_size,
                              hipStream_t stream) {
    const float* x  = (const float*)d_in[0];
    const int*   ei = (const int*)d_in[1];
    const float* W1 = (const float*)d_in[2];
    const float* b1 = (const float*)d_in[3];
    const float* W2 = (const float*)d_in[4];
    const float* b2 = (const float*)d_in[5];

    const int hid    = in_sizes[3];            // 128
    const int in_ch  = in_sizes[2] / hid;      // 128
    const int out_ch = in_sizes[5];            // 64
    const int N      = in_sizes[0] / in_ch;    // 50000
    const int E      = in_sizes[1] / 2;        // 800000

    // workspace carve-out
    char* wsp = (char*)d_ws;
    auto alloc = [&](size_t bytes) -> char* {
        char* p = wsp;
        wsp += (bytes + 255) & ~(size_t)255;
        return p;
    };
    __half* h1       = (__half*)alloc((size_t)N * hid * 2);     // fp16, gathered
    float*  hmid     = (float*)alloc((size_t)N * hid * 4);      // fp32, streamed
    __half* h2       = (__half*)alloc((size_t)N * out_ch * 2);  // fp16, gathered
    int*   hist      = (int*)alloc((size_t)N * 4);
    int*   cursor    = (int*)alloc((size_t)N * 4);
    int*   row_start = (int*)alloc((size_t)(N + 1) * 4);
    float* dis       = (float*)alloc((size_t)N * 4);
    int*   partial   = (int*)alloc(1024);
    int*   enorm     = (int*)alloc((size_t)2 * E * 4);  // normalized int32 edges
    int*   csr_src   = (int*)alloc((size_t)E * 4);

    const int NB = (N + 255) / 256;  // 196 (must be <= 256)

    // --- edge dtype normalization + hist zero ---
    normalize_kernel<<<2048, 256, 0, stream>>>(ei, enorm, 2 * E, hist, N);
    const int* esrc = enorm;
    const int* edst = enorm + E;

    // --- CSR build ---
    hist_kernel<<<1024, 256, 0, stream>>>(edst, E, hist);
    scan1_kernel<<<NB, 256, 0, stream>>>(hist, row_start, partial, N);
    scan23_kernel<<<NB, 256, 0, stream>>>(row_start, partial, hist, dis, cursor, N, E, NB);
    scatter_kernel<<<1024, 256, 0, stream>>>(esrc, edst, E, row_start, cursor, csr_src);

    // --- layer 1 ---
    gemm_tile<128, 128, 8, 8, true><<<(N + 127) / 128, 256, 0, stream>>>(
        x, W1, dis, h1, N, in_ch, hid);
    agg1_kernel<<<2048, 256, 0, stream>>>(h1, dis, row_start, csr_src, b1, hmid, N);

    // --- layer 2 ---
    gemm_tile<128, 64, 8, 4, true><<<(N + 127) / 128, 256, 0, stream>>>(
        hmid, W2, dis, h2, N, hid, out_ch);
    agg2_kernel<<<2048, 256, 0, stream>>>(h2, dis, row_start, csr_src, b2,
                                          (float*)d_out, N);
}

// Round 12
// 257.966 us; speedup vs baseline: 1.3186x; 1.0687x over previous
//
#include <hip/hip_runtime.h>
#include <hip/hip_fp16.h>
#include <math.h>

// ---------------------------------------------------------------------------
// 2-layer GCN: out = A_hat( tanh( A_hat(X W1) + b1 ) ) W2 + b2
// A_hat = D^-1/2 (A + I) D^-1/2, dst-CSR built each call.
// h' = (X W) * dis[row] folded into GEMM epilogue; agg loop = pure gather+add.
// GEMMs use fp16 MFMA (v_mfma_f32_16x16x32_f16, fp32 accum); gathered tensors
// (h1', h2') and the inter-layer hmid stored fp16; aggregation accum fp32.
// Agg kernels: indices vector-loaded per 64 edges, __shfl-broadcast -> 8
// independent row-gathers in flight (validated R8: agg1 66->~30us ladder).
// ---------------------------------------------------------------------------

typedef _Float16 fh8 __attribute__((ext_vector_type(8)));
typedef float f4 __attribute__((ext_vector_type(4)));

// emit clean int32 edge array regardless of int64/int32 input layout; zero hist.
__global__ __launch_bounds__(256) void normalize_kernel(const int* __restrict__ ei32,
                                                        int* __restrict__ out, int n2,
                                                        int* __restrict__ hist, int nh) {
    __shared__ int s_is64;
    if (threadIdx.x == 0) {
        int is64 = 1;
        for (int k = 1; k < 64; k += 2)
            if (ei32[k] != 0) { is64 = 0; break; }
        s_is64 = is64;
    }
    __syncthreads();
    const int is64 = s_is64;
    for (int i = blockIdx.x * blockDim.x + threadIdx.x; i < n2;
         i += gridDim.x * blockDim.x) {
        out[i] = is64 ? ei32[2 * i] : ei32[i];
        if (i < nh) hist[i] = 0;
    }
}

__global__ __launch_bounds__(256) void hist_kernel(const int* __restrict__ dst, int E,
                                                   int* __restrict__ hist) {
    for (int i = blockIdx.x * blockDim.x + threadIdx.x; i < E;
         i += gridDim.x * blockDim.x) {
        atomicAdd(&hist[dst[i]], 1);
    }
}

// Block-level inclusive scan -> exclusive per-element + block total.
__global__ __launch_bounds__(256) void scan1_kernel(const int* __restrict__ hist,
                                                    int* __restrict__ row_start,
                                                    int* __restrict__ partial, int n) {
    __shared__ int tmp[256];
    int t = threadIdx.x;
    int i = blockIdx.x * 256 + t;
    int v = (i < n) ? hist[i] : 0;
    tmp[t] = v;
    __syncthreads();
    for (int off = 1; off < 256; off <<= 1) {
        int add = (t >= off) ? tmp[t - off] : 0;
        __syncthreads();
        tmp[t] += add;
        __syncthreads();
    }
    if (i < n) row_start[i] = tmp[t] - v;          // exclusive
    if (t == 255) partial[blockIdx.x] = tmp[255];  // block total
}

// Merged scan2+scan3: every block redundantly scans the <=256 block-partials,
// then finalizes row_start, dis, cursor.
__global__ __launch_bounds__(256) void scan23_kernel(int* __restrict__ row_start,
                                                     const int* __restrict__ partial,
                                                     const int* __restrict__ hist,
                                                     float* __restrict__ dis,
                                                     int* __restrict__ cursor,
                                                     int n, int E, int nb) {
    __shared__ int offs[256];
    int t = threadIdx.x;
    int v = (t < nb) ? partial[t] : 0;
    offs[t] = v;
    __syncthreads();
    for (int off = 1; off < 256; off <<= 1) {
        int add = (t >= off) ? offs[t - off] : 0;
        __syncthreads();
        offs[t] += add;
        __syncthreads();
    }
    int incl = offs[t];
    __syncthreads();
    offs[t] = incl - v;  // exclusive block offsets
    __syncthreads();

    int i = blockIdx.x * 256 + t;
    if (i < n) {
        row_start[i] += offs[i >> 8];
        dis[i] = rsqrtf((float)(hist[i] + 1));  // +1: self-loop; always > 0
        cursor[i] = 0;
    }
    if (i == 0) row_start[n] = E;
}

__global__ __launch_bounds__(256) void scatter_kernel(const int* __restrict__ src,
                                                      const int* __restrict__ dst, int E,
                                                      const int* __restrict__ row_start,
                                                      int* __restrict__ cursor,
                                                      int* __restrict__ csr_src) {
    for (int i = blockIdx.x * blockDim.x + threadIdx.x; i < E;
         i += gridDim.x * blockDim.x) {
        int d = dst[i];
        int pos = atomicAdd(&cursor[d], 1);
        csr_src[row_start[d] + pos] = src[i];
    }
}

// ---------------------------------------------------------------------------
// prep_w: W1[K][N1] -> w1t fp16 [N1][K]; W2[K][N2] -> w2t fp16 [N2][K].
// K = in_ch = hid = 128. Tiny (24K elems).
// ---------------------------------------------------------------------------
__global__ __launch_bounds__(256) void prep_w_kernel(const float* __restrict__ W1,
                                                     const float* __restrict__ W2,
                                                     __half* __restrict__ w1t,
                                                     __half* __restrict__ w2t,
                                                     int K, int N1, int N2) {
    int total1 = K * N1, total2 = K * N2;
    for (int i = blockIdx.x * 256 + threadIdx.x; i < total1 + total2;
         i += gridDim.x * 256) {
        if (i < total1) {
            int c = i / K, k = i % K;
            w1t[i] = __float2half(W1[(size_t)k * N1 + c]);
        } else {
            int j = i - total1;
            int c = j / K, k = j % K;
            w2t[j] = __float2half(W2[(size_t)k * N2 + c]);
        }
    }
}

// ---------------------------------------------------------------------------
// MFMA fp16 GEMM: C[M][BN] = fp16( (A[M][128] * W) * scale[row] ).
// W pre-transposed fp16 [BN][128]. Block = 256 thr = 4 waves, BM = 64
// (wave = 16-row strip, all BN cols). K = 128 = 4 MFMA k-steps, single stage.
// Fragment mappings (guide-verified, m89): A row=lane&15, k=(lane>>4)*8+j;
// B col=lane&15, same k; D col=lane&15, row=(lane>>4)*4+reg.
// LDS stride padded to 136 halves (68 dwords === 4 mod 32 -> 2-way, free).
// ---------------------------------------------------------------------------
template <int BN, bool AH>
__global__ __launch_bounds__(256) void gemm_mfma(const void* __restrict__ Av,
                                                 const __half* __restrict__ WT,
                                                 const float* __restrict__ scale,
                                                 __half* __restrict__ C, int M) {
    constexpr int K = 128;
    constexpr int LDK = K + 8;  // padded stride in halves
    const int t = threadIdx.x;
    const int wv = t >> 6;
    const int lane = t & 63;
    const int row0 = blockIdx.x * 64;

    __shared__ __half As[4][16][LDK];
    __shared__ __half Ws[BN][LDK];

    // stage W^T (coalesced 16B vector loads, padded LDS rows)
    {
        constexpr int V = BN * K / 8;
        for (int i = t; i < V; i += 256) {
            int c = i / (K / 8);
            int v8 = i % (K / 8);
            fh8 w = *(const fh8*)&WT[(size_t)c * K + v8 * 8];
            *(fh8*)&Ws[c][v8 * 8] = w;
        }
    }
    // stage A strip: 16 rows/wave, fp32->fp16 convert (or fp16 copy)
    {
        for (int idx = lane; idx < 16 * 64; idx += 64) {
            int r = idx >> 6;   // row in strip
            int c2 = idx & 63;  // half2 column
            int grow = row0 + wv * 16 + r;
            __half2 h;
            if (AH) {
                h = (grow < M) ? ((const __half2*)Av)[(size_t)grow * 64 + c2]
                               : __floats2half2_rn(0.f, 0.f);
            } else {
                float2 f = make_float2(0.f, 0.f);
                if (grow < M) f = ((const float2*)Av)[(size_t)grow * 64 + c2];
                h = __floats2half2_rn(f.x, f.y);
            }
            *(__half2*)&As[wv][r][c2 * 2] = h;
        }
    }
    __syncthreads();

    const int lr = lane & 15;        // A row / B col / D col
    const int lk = (lane >> 4) * 8;  // k sub-offset

    fh8 af[4];
#pragma unroll
    for (int ks = 0; ks < 4; ks++)
        af[ks] = *(const fh8*)&As[wv][lr][ks * 32 + lk];

    f4 acc[BN / 16];
#pragma unroll
    for (int nt = 0; nt < BN / 16; nt++) acc[nt] = (f4){0.f, 0.f, 0.f, 0.f};

#pragma unroll
    for (int nt = 0; nt < BN / 16; nt++) {
#pragma unroll
        for (int ks = 0; ks < 4; ks++) {
            fh8 bf = *(const fh8*)&Ws[nt * 16 + lr][ks * 32 + lk];
            acc[nt] = __builtin_amdgcn_mfma_f32_16x16x32_f16(af[ks], bf, acc[nt], 0, 0, 0);
        }
    }

    // epilogue: D row = 4*(lane>>4)+j, col = nt*16+lr; *scale[row] -> fp16
    const int rbase = row0 + wv * 16 + (lane >> 4) * 4;
#pragma unroll
    for (int j = 0; j < 4; j++) {
        int grow = rbase + j;
        if (grow < M) {
            float sc = scale[grow];
#pragma unroll
            for (int nt = 0; nt < BN / 16; nt++) {
                C[(size_t)grow * BN + nt * 16 + lr] = __float2half(acc[nt][j] * sc);
            }
        }
    }
}

// ---------------------------------------------------------------------------
// Aggregation layer 1: 128 ch, 1 wave/node, lane = 2 ch (__half2, fp32 acc).
// Indices vector-loaded (<=64/iter), broadcast via __shfl; 8 gathers in flight.
// Epilogue: *dis, +b1, tanh -> fp16 hmid.
// ---------------------------------------------------------------------------
__global__ __launch_bounds__(256) void agg1_kernel(const __half* __restrict__ hs,
                                                   const float* __restrict__ dis,
                                                   const int* __restrict__ row_start,
                                                   const int* __restrict__ csr_src,
                                                   const float* __restrict__ b1,
                                                   __half* __restrict__ hout, int n) {
    const int wid = threadIdx.x >> 6;
    const int lane = threadIdx.x & 63;
    const __half2* hv = (const __half2*)hs;

    for (int node = blockIdx.x * 4 + wid; node < n; node += gridDim.x * 4) {
        float2 acc = __half22float2(hv[(size_t)node * 64 + lane]);  // self-loop term

        const int e0 = row_start[node];
        const int deg = row_start[node + 1] - e0;

        for (int base = 0; base < deg; base += 64) {
            const int cnt = min(64, deg - base);
            int myidx = 0;
            if (lane < cnt) myidx = csr_src[e0 + base + lane];

            int k = 0;
            for (; k + 8 <= cnt; k += 8) {
                int s0 = __shfl(myidx, k + 0);
                int s1 = __shfl(myidx, k + 1);
                int s2 = __shfl(myidx, k + 2);
                int s3 = __shfl(myidx, k + 3);
                int s4 = __shfl(myidx, k + 4);
                int s5 = __shfl(myidx, k + 5);
                int s6 = __shfl(myidx, k + 6);
                int s7 = __shfl(myidx, k + 7);
                float2 v0 = __half22float2(hv[(size_t)s0 * 64 + lane]);
                float2 v1 = __half22float2(hv[(size_t)s1 * 64 + lane]);
                float2 v2 = __half22float2(hv[(size_t)s2 * 64 + lane]);
                float2 v3 = __half22float2(hv[(size_t)s3 * 64 + lane]);
                float2 v4 = __half22float2(hv[(size_t)s4 * 64 + lane]);
                float2 v5 = __half22float2(hv[(size_t)s5 * 64 + lane]);
                float2 v6 = __half22float2(hv[(size_t)s6 * 64 + lane]);
                float2 v7 = __half22float2(hv[(size_t)s7 * 64 + lane]);
                acc.x += ((v0.x + v1.x) + (v2.x + v3.x)) + ((v4.x + v5.x) + (v6.x + v7.x));
                acc.y += ((v0.y + v1.y) + (v2.y + v3.y)) + ((v4.y + v5.y) + (v6.y + v7.y));
            }
            for (; k < cnt; ++k) {
                int s = __shfl(myidx, k);
                float2 v = __half22float2(hv[(size_t)s * 64 + lane]);
                acc.x += v.x;
                acc.y += v.y;
            }
        }
        float dd = dis[node];
        float2 bb = ((const float2*)b1)[lane];
        ((__half2*)hout)[(size_t)node * 64 + lane] =
            __floats2half2_rn(tanhf(acc.x * dd + bb.x), tanhf(acc.y * dd + bb.y));
    }
}

// Aggregation layer 2: 64 ch, 1 wave/node, lane = 1 ch (fp16, fp32 acc). +b2.
__global__ __launch_bounds__(256) void agg2_kernel(const __half* __restrict__ hs,
                                                   const float* __restrict__ dis,
                                                   const int* __restrict__ row_start,
                                                   const int* __restrict__ csr_src,
                                                   const float* __restrict__ b2,
                                                   float* __restrict__ out, int n) {
    const int wid = threadIdx.x >> 6;
    const int lane = threadIdx.x & 63;

    for (int node = blockIdx.x * 4 + wid; node < n; node += gridDim.x * 4) {
        float acc = __half2float(hs[(size_t)node * 64 + lane]);  // self-loop term

        const int e0 = row_start[node];
        const int deg = row_start[node + 1] - e0;

        for (int base = 0; base < deg; base += 64) {
            const int cnt = min(64, deg - base);
            int myidx = 0;
            if (lane < cnt) myidx = csr_src[e0 + base + lane];

            int k = 0;
            for (; k + 8 <= cnt; k += 8) {
                int s0 = __shfl(myidx, k + 0);
                int s1 = __shfl(myidx, k + 1);
                int s2 = __shfl(myidx, k + 2);
                int s3 = __shfl(myidx, k + 3);
                int s4 = __shfl(myidx, k + 4);
                int s5 = __shfl(myidx, k + 5);
                int s6 = __shfl(myidx, k + 6);
                int s7 = __shfl(myidx, k + 7);
                float v0 = __half2float(hs[(size_t)s0 * 64 + lane]);
                float v1 = __half2float(hs[(size_t)s1 * 64 + lane]);
                float v2 = __half2float(hs[(size_t)s2 * 64 + lane]);
                float v3 = __half2float(hs[(size_t)s3 * 64 + lane]);
                float v4 = __half2float(hs[(size_t)s4 * 64 + lane]);
                float v5 = __half2float(hs[(size_t)s5 * 64 + lane]);
                float v6 = __half2float(hs[(size_t)s6 * 64 + lane]);
                float v7 = __half2float(hs[(size_t)s7 * 64 + lane]);
                acc += ((v0 + v1) + (v2 + v3)) + ((v4 + v5) + (v6 + v7));
            }
            for (; k < cnt; ++k) {
                int s = __shfl(myidx, k);
                acc += __half2float(hs[(size_t)s * 64 + lane]);
            }
        }
        out[(size_t)node * 64 + lane] = acc * dis[node] + b2[lane];
    }
}

// ---------------------------------------------------------------------------
extern "C" void kernel_launch(void* const* d_in, const int* in_sizes, int n_in,
                              void* d_out, int out_size, void* d_ws, size_t ws_size,
                              hipStream_t stream) {
    const float* x  = (const float*)d_in[0];
    const int*   ei = (const int*)d_in[1];
    const float* W1 = (const float*)d_in[2];
    const float* b1 = (const float*)d_in[3];
    const float* W2 = (const float*)d_in[4];
    const float* b2 = (const float*)d_in[5];

    const int hid    = in_sizes[3];            // 128
    const int in_ch  = in_sizes[2] / hid;      // 128
    const int out_ch = in_sizes[5];            // 64
    const int N      = in_sizes[0] / in_ch;    // 50000
    const int E      = in_sizes[1] / 2;        // 800000

    // workspace carve-out
    char* wsp = (char*)d_ws;
    auto alloc = [&](size_t bytes) -> char* {
        char* p = wsp;
        wsp += (bytes + 255) & ~(size_t)255;
        return p;
    };
    __half* h1       = (__half*)alloc((size_t)N * hid * 2);     // fp16, gathered
    __half* hmid     = (__half*)alloc((size_t)N * hid * 2);     // fp16, streamed
    __half* h2       = (__half*)alloc((size_t)N * out_ch * 2);  // fp16, gathered
    __half* w1t      = (__half*)alloc((size_t)hid * in_ch * 2); // W1^T fp16 [hid][128]
    __half* w2t      = (__half*)alloc((size_t)out_ch * hid * 2);// W2^T fp16 [64][128]
    int*   hist      = (int*)alloc((size_t)N * 4);
    int*   cursor    = (int*)alloc((size_t)N * 4);
    int*   row_start = (int*)alloc((size_t)(N + 1) * 4);
    float* dis       = (float*)alloc((size_t)N * 4);
    int*   partial   = (int*)alloc(1024);
    int*   enorm     = (int*)alloc((size_t)2 * E * 4);  // normalized int32 edges
    int*   csr_src   = (int*)alloc((size_t)E * 4);

    const int NB = (N + 255) / 256;  // 196 (must be <= 256)

    // --- edge dtype normalization + hist zero; weight transpose/convert ---
    normalize_kernel<<<2048, 256, 0, stream>>>(ei, enorm, 2 * E, hist, N);
    prep_w_kernel<<<96, 256, 0, stream>>>(W1, W2, w1t, w2t, in_ch, hid, out_ch);
    const int* esrc = enorm;
    const int* edst = enorm + E;

    // --- CSR build ---
    hist_kernel<<<1024, 256, 0, stream>>>(edst, E, hist);
    scan1_kernel<<<NB, 256, 0, stream>>>(hist, row_start, partial, N);
    scan23_kernel<<<NB, 256, 0, stream>>>(row_start, partial, hist, dis, cursor, N, E, NB);
    scatter_kernel<<<1024, 256, 0, stream>>>(esrc, edst, E, row_start, cursor, csr_src);

    // --- layer 1 ---
    gemm_mfma<128, false><<<(N + 63) / 64, 256, 0, stream>>>(x, w1t, dis, h1, N);
    agg1_kernel<<<2048, 256, 0, stream>>>(h1, dis, row_start, csr_src, b1, hmid, N);

    // --- layer 2 ---
    gemm_mfma<64, true><<<(N + 63) / 64, 256, 0, stream>>>(hmid, w2t, dis, h2, N);
    agg2_kernel<<<2048, 256, 0, stream>>>(h2, dis, row_start, csr_src, b2,
                                          (float*)d_out, N);
}